// Round 1
// baseline (283.380 us; speedup 1.0000x reference)
//
#include <hip/hip_runtime.h>
#include <hip/hip_bf16.h>

typedef __bf16 bf16;
typedef __bf16 bf16x8 __attribute__((ext_vector_type(8)));
typedef __bf16 bf16x4 __attribute__((ext_vector_type(4)));
typedef float f32x4 __attribute__((ext_vector_type(4)));

#define MFMA16(a, b, c) __builtin_amdgcn_mfma_f32_16x16x32_bf16(a, b, c, 0, 0, 0)

// ---------------- fp32 -> bf16 conversion ----------------
__global__ void cvt_kernel(const float* __restrict__ in, bf16* __restrict__ out, int n4) {
    int i = blockIdx.x * blockDim.x + threadIdx.x;
    if (i < n4) {
        float4 f = ((const float4*)in)[i];
        bf16x4 o;
        o[0] = (bf16)f.x; o[1] = (bf16)f.y; o[2] = (bf16)f.z; o[3] = (bf16)f.w;
        ((bf16x4*)out)[i] = o;
    }
}

// ---------------- GEMM1: qkv = x @ w_qkv^T, scatter to q/k/v [B][H][N][D] ----------------
// A: [4096][1024] bf16, Bm: [3072][1024] bf16 (row-major, K contiguous)
__global__ __launch_bounds__(256, 2) void gemm_qkv(
    const bf16* __restrict__ A, const bf16* __restrict__ Bm,
    bf16* __restrict__ qo, bf16* __restrict__ ko, bf16* __restrict__ vo)
{
    const int K = 1024;
    __shared__ bf16 As[128][40];  // pad 32 -> 40 (stride 80B, 16B-aligned, 2-way max)
    __shared__ bf16 Bs[128][40];
    const int tid = threadIdx.x;
    const int wave = tid >> 6, lane = tid & 63;
    const int lrow = lane & 15, quad = lane >> 4;
    const int wm = (wave >> 1) * 64, wn = (wave & 1) * 64;
    const int si = tid >> 2, sk = (tid & 3) * 8;

    const bf16* Ap = A + (long)(blockIdx.x * 128 + si) * K + sk;
    const bf16* Bp = Bm + (long)(blockIdx.y * 128 + si) * K + sk;

    f32x4 acc[4][4] = {};

    for (int k0 = 0; k0 < K; k0 += 32) {
        bf16x8 a0 = *(const bf16x8*)(Ap + k0);
        bf16x8 a1 = *(const bf16x8*)(Ap + (long)64 * K + k0);
        bf16x8 b0 = *(const bf16x8*)(Bp + k0);
        bf16x8 b1 = *(const bf16x8*)(Bp + (long)64 * K + k0);
        __syncthreads();
        *(bf16x8*)&As[si][sk]      = a0;
        *(bf16x8*)&As[si + 64][sk] = a1;
        *(bf16x8*)&Bs[si][sk]      = b0;
        *(bf16x8*)&Bs[si + 64][sk] = b1;
        __syncthreads();
        bf16x8 af[4], bfr[4];
#pragma unroll
        for (int i = 0; i < 4; i++) af[i] = *(const bf16x8*)&As[wm + i * 16 + lrow][quad * 8];
#pragma unroll
        for (int j = 0; j < 4; j++) bfr[j] = *(const bf16x8*)&Bs[wn + j * 16 + lrow][quad * 8];
#pragma unroll
        for (int i = 0; i < 4; i++)
#pragma unroll
            for (int j = 0; j < 4; j++)
                acc[i][j] = MFMA16(af[i], bfr[j], acc[i][j]);
    }

    // epilogue: C row = gm (flattened b,n), col o -> (s,h,d); q scaled by 0.125 (exact pow2)
    const int gm0 = blockIdx.x * 128 + wm;
    const int go0 = blockIdx.y * 128 + wn;
#pragma unroll
    for (int i = 0; i < 4; i++) {
#pragma unroll
        for (int r = 0; r < 4; r++) {
            int gm = gm0 + i * 16 + quad * 4 + r;
            int b = gm >> 11, n = gm & 2047;
#pragma unroll
            for (int j = 0; j < 4; j++) {
                int o = go0 + j * 16 + lrow;
                int s = o >> 10, rem = o & 1023;
                int h = rem >> 6, d = rem & 63;
                long idx = (((long)(b * 16 + h)) * 2048 + n) * 64 + d;
                float v = acc[i][j][r];
                if (s == 0)      qo[idx] = (bf16)(v * 0.125f);
                else if (s == 1) ko[idx] = (bf16)v;
                else             vo[idx] = (bf16)v;
            }
        }
    }
}

// ---------------- Flash attention: one block per (bh, 128-row q tile) ----------------
// q (pre-scaled), k, v: [B][H][N][D] bf16; o: [B][N][H*D] bf16
__global__ __launch_bounds__(256, 2) void attn_kernel(
    const bf16* __restrict__ q, const bf16* __restrict__ k,
    const bf16* __restrict__ v, bf16* __restrict__ o)
{
    __shared__ bf16 Ks[64][72];      // [kpos][d], pad 64->72
    __shared__ bf16 Vts[64][72];     // [d][kpos] (transposed), pad
    __shared__ bf16 Ps[4][32][72];   // per-wave P round-trip; also Q staging (128x72 fits)

    const int tid = threadIdx.x, wave = tid >> 6, lane = tid & 63;
    const int lrow = lane & 15, quad = lane >> 4;
    const int bh = blockIdx.y, qt = blockIdx.x;
    const bf16* Qp = q + ((long)bh * 2048 + qt * 128) * 64;
    const bf16* Kp = k + (long)bh * 2048 * 64;
    const bf16* Vp = v + (long)bh * 2048 * 64;

    // ---- stage Q (128x64) into Ps region, load per-wave A-fragments, keep in regs ----
    bf16(*Qs)[72] = (bf16(*)[72]) (&Ps[0][0][0]);
    {
        int r0 = tid >> 3, g = (tid & 7) * 8;
#pragma unroll
        for (int p = 0; p < 4; p++)
            *(bf16x8*)&Qs[r0 + p * 32][g] = *(const bf16x8*)&Qp[(r0 + p * 32) * 64 + g];
    }
    __syncthreads();
    bf16x8 qf[2][2];
#pragma unroll
    for (int t = 0; t < 2; t++)
#pragma unroll
        for (int ks = 0; ks < 2; ks++)
            qf[t][ks] = *(const bf16x8*)&Qs[wave * 32 + t * 16 + lrow][ks * 32 + quad * 8];

    float mst[2][4], lst[2][4];
    f32x4 oacc[2][4] = {};
#pragma unroll
    for (int t = 0; t < 2; t++)
#pragma unroll
        for (int r = 0; r < 4; r++) { mst[t][r] = -1e30f; lst[t][r] = 0.0f; }

    for (int kv = 0; kv < 32; kv++) {
        const bf16* Kt = Kp + kv * 64 * 64;
        const bf16* Vt = Vp + kv * 64 * 64;
        int r0 = tid >> 3, g = (tid & 7) * 8;
        bf16x8 k0v = *(const bf16x8*)&Kt[r0 * 64 + g];
        bf16x8 k1v = *(const bf16x8*)&Kt[(r0 + 32) * 64 + g];
        bf16x8 v0v = *(const bf16x8*)&Vt[r0 * 64 + g];
        bf16x8 v1v = *(const bf16x8*)&Vt[(r0 + 32) * 64 + g];
        __syncthreads();  // prev iter's LDS reads (and iter-0 qf loads) are done
        *(bf16x8*)&Ks[r0][g]      = k0v;
        *(bf16x8*)&Ks[r0 + 32][g] = k1v;
#pragma unroll
        for (int j = 0; j < 8; j++) {
            Vts[g + j][r0]      = v0v[j];
            Vts[g + j][r0 + 32] = v1v[j];
        }
        __syncthreads();

        // ---- S = Q K^T (q pre-scaled) : each wave 32 rows x 64 keys ----
        f32x4 sacc[2][4] = {};
#pragma unroll
        for (int ks = 0; ks < 2; ks++) {
            bf16x8 kf[4];
#pragma unroll
            for (int n = 0; n < 4; n++) kf[n] = *(const bf16x8*)&Ks[n * 16 + lrow][ks * 32 + quad * 8];
#pragma unroll
            for (int t = 0; t < 2; t++)
#pragma unroll
                for (int n = 0; n < 4; n++)
                    sacc[t][n] = MFMA16(qf[t][ks], kf[n], sacc[t][n]);
        }

        // ---- online softmax; row stats live in a 16-lane quad ----
#pragma unroll
        for (int t = 0; t < 2; t++) {
#pragma unroll
            for (int r = 0; r < 4; r++) {
                float mx = fmaxf(fmaxf(sacc[t][0][r], sacc[t][1][r]),
                                 fmaxf(sacc[t][2][r], sacc[t][3][r]));
#pragma unroll
                for (int off = 1; off < 16; off <<= 1) mx = fmaxf(mx, __shfl_xor(mx, off, 64));
                float mnew = fmaxf(mst[t][r], mx);
                float alpha = __expf(mst[t][r] - mnew);
                mst[t][r] = mnew;
                float rsum = 0.0f;
#pragma unroll
                for (int n = 0; n < 4; n++) {
                    float pv = __expf(sacc[t][n][r] - mnew);
                    sacc[t][n][r] = pv;
                    rsum += pv;
                }
#pragma unroll
                for (int off = 1; off < 16; off <<= 1) rsum += __shfl_xor(rsum, off, 64);
                lst[t][r] = lst[t][r] * alpha + rsum;
#pragma unroll
                for (int n = 0; n < 4; n++) oacc[t][n][r] *= alpha;
            }
        }

        // ---- P (C-layout) -> LDS -> A-layout ----
#pragma unroll
        for (int t = 0; t < 2; t++)
#pragma unroll
            for (int n = 0; n < 4; n++)
#pragma unroll
                for (int r = 0; r < 4; r++)
                    Ps[wave][t * 16 + quad * 4 + r][n * 16 + lrow] = (bf16)sacc[t][n][r];
        __syncthreads();

        // ---- O += P V ----
#pragma unroll
        for (int ks2 = 0; ks2 < 2; ks2++) {
            bf16x8 pf[2], vf[4];
#pragma unroll
            for (int t = 0; t < 2; t++) pf[t] = *(const bf16x8*)&Ps[wave][t * 16 + lrow][ks2 * 32 + quad * 8];
#pragma unroll
            for (int n = 0; n < 4; n++) vf[n] = *(const bf16x8*)&Vts[n * 16 + lrow][ks2 * 32 + quad * 8];
#pragma unroll
            for (int t = 0; t < 2; t++)
#pragma unroll
                for (int n = 0; n < 4; n++)
                    oacc[t][n] = MFMA16(pf[t], vf[n], oacc[t][n]);
        }
    }

    // ---- epilogue: O /= l, write [B][N][H*D] bf16 ----
    const int b = bh >> 4, h = bh & 15;
    const int qbase = qt * 128 + wave * 32;
#pragma unroll
    for (int t = 0; t < 2; t++)
#pragma unroll
        for (int r = 0; r < 4; r++) {
            int n = qbase + t * 16 + quad * 4 + r;
            float inv = 1.0f / lst[t][r];
#pragma unroll
            for (int j = 0; j < 4; j++) {
                int d = j * 16 + lrow;
                o[((long)(b * 2048 + n)) * 1024 + h * 64 + d] = (bf16)(oacc[t][j][r] * inv);
            }
        }
}

// ---------------- GEMM2: out = attn_out @ w_proj^T (fp32 out) ----------------
__global__ __launch_bounds__(256, 2) void gemm_proj(
    const bf16* __restrict__ A, const bf16* __restrict__ Bm, float* __restrict__ out)
{
    const int K = 1024;
    __shared__ bf16 As[128][40];
    __shared__ bf16 Bs[128][40];
    const int tid = threadIdx.x;
    const int wave = tid >> 6, lane = tid & 63;
    const int lrow = lane & 15, quad = lane >> 4;
    const int wm = (wave >> 1) * 64, wn = (wave & 1) * 64;
    const int si = tid >> 2, sk = (tid & 3) * 8;

    const bf16* Ap = A + (long)(blockIdx.x * 128 + si) * K + sk;
    const bf16* Bp = Bm + (long)(blockIdx.y * 128 + si) * K + sk;

    f32x4 acc[4][4] = {};

    for (int k0 = 0; k0 < K; k0 += 32) {
        bf16x8 a0 = *(const bf16x8*)(Ap + k0);
        bf16x8 a1 = *(const bf16x8*)(Ap + (long)64 * K + k0);
        bf16x8 b0 = *(const bf16x8*)(Bp + k0);
        bf16x8 b1 = *(const bf16x8*)(Bp + (long)64 * K + k0);
        __syncthreads();
        *(bf16x8*)&As[si][sk]      = a0;
        *(bf16x8*)&As[si + 64][sk] = a1;
        *(bf16x8*)&Bs[si][sk]      = b0;
        *(bf16x8*)&Bs[si + 64][sk] = b1;
        __syncthreads();
        bf16x8 af[4], bfr[4];
#pragma unroll
        for (int i = 0; i < 4; i++) af[i] = *(const bf16x8*)&As[wm + i * 16 + lrow][quad * 8];
#pragma unroll
        for (int j = 0; j < 4; j++) bfr[j] = *(const bf16x8*)&Bs[wn + j * 16 + lrow][quad * 8];
#pragma unroll
        for (int i = 0; i < 4; i++)
#pragma unroll
            for (int j = 0; j < 4; j++)
                acc[i][j] = MFMA16(af[i], bfr[j], acc[i][j]);
    }

    const int gm0 = blockIdx.x * 128 + wm;
    const int go0 = blockIdx.y * 128 + wn;
#pragma unroll
    for (int i = 0; i < 4; i++)
#pragma unroll
        for (int r = 0; r < 4; r++) {
            int gm = gm0 + i * 16 + quad * 4 + r;
#pragma unroll
            for (int j = 0; j < 4; j++) {
                int o = go0 + j * 16 + lrow;
                out[(long)gm * 1024 + o] = acc[i][j][r];
            }
        }
}

// ---------------- launch ----------------
extern "C" void kernel_launch(void* const* d_in, const int* in_sizes, int n_in,
                              void* d_out, int out_size, void* d_ws, size_t ws_size,
                              hipStream_t stream) {
    const float* x      = (const float*)d_in[0];   // [2,2048,1024]
    const float* w_qkv  = (const float*)d_in[1];   // [3072,1024]
    const float* w_proj = (const float*)d_in[2];   // [1024,1024]
    float* out = (float*)d_out;                    // [2,2048,1024]

    bf16* ws = (bf16*)d_ws;
    bf16* xb     = ws;                       // 4096*1024
    bf16* wqkvb  = xb + 4096 * 1024;         // 3072*1024
    bf16* wprojb = wqkvb + 3072 * 1024;      // 1024*1024
    bf16* qb     = wprojb + 1024 * 1024;     // [2][16][2048][64]
    bf16* kb     = qb + 2 * 16 * 2048 * 64;
    bf16* vb     = kb + 2 * 16 * 2048 * 64;
    bf16* ob     = vb + 2 * 16 * 2048 * 64;  // 4096*1024

    cvt_kernel<<<(4096 * 1024 / 4 + 255) / 256, 256, 0, stream>>>(x, xb, 4096 * 1024 / 4);
    cvt_kernel<<<(3072 * 1024 / 4 + 255) / 256, 256, 0, stream>>>(w_qkv, wqkvb, 3072 * 1024 / 4);
    cvt_kernel<<<(1024 * 1024 / 4 + 255) / 256, 256, 0, stream>>>(w_proj, wprojb, 1024 * 1024 / 4);

    gemm_qkv<<<dim3(32, 24), 256, 0, stream>>>(xb, wqkvb, qb, kb, vb);
    attn_kernel<<<dim3(16, 32), 256, 0, stream>>>(qb, kb, vb, ob);
    gemm_proj<<<dim3(32, 8), 256, 0, stream>>>(ob, wprojb, out);
}

// Round 2
// 205.312 us; speedup vs baseline: 1.3802x; 1.3802x over previous
//
#include <hip/hip_runtime.h>
#include <hip/hip_bf16.h>

typedef __bf16 bf16;
typedef __bf16 bf16x8 __attribute__((ext_vector_type(8)));
typedef __bf16 bf16x4 __attribute__((ext_vector_type(4)));
typedef float f32x4 __attribute__((ext_vector_type(4)));

#define MFMA16(a, b, c) __builtin_amdgcn_mfma_f32_16x16x32_bf16(a, b, c, 0, 0, 0)

// ---------------- fp32 -> bf16 conversion ----------------
__global__ void cvt_kernel(const float* __restrict__ in, bf16* __restrict__ out, int n4) {
    int i = blockIdx.x * blockDim.x + threadIdx.x;
    if (i < n4) {
        float4 f = ((const float4*)in)[i];
        bf16x4 o;
        o[0] = (bf16)f.x; o[1] = (bf16)f.y; o[2] = (bf16)f.z; o[3] = (bf16)f.w;
        ((bf16x4*)out)[i] = o;
    }
}

// ---------------- GEMM1: qkv = x @ w_qkv^T, scatter to q/k [B][H][N][D], v [B][H][D][N] ----
__global__ __launch_bounds__(256, 2) void gemm_qkv(
    const bf16* __restrict__ A, const bf16* __restrict__ Bm,
    bf16* __restrict__ qo, bf16* __restrict__ ko, bf16* __restrict__ vo)
{
    const int K = 1024;
    __shared__ bf16 As[128][40];
    __shared__ bf16 Bs[128][40];
    const int tid = threadIdx.x;
    const int wave = tid >> 6, lane = tid & 63;
    const int lrow = lane & 15, quad = lane >> 4;
    const int wm = (wave >> 1) * 64, wn = (wave & 1) * 64;
    const int si = tid >> 2, sk = (tid & 3) * 8;

    const bf16* Ap = A + (long)(blockIdx.x * 128 + si) * K + sk;
    const bf16* Bp = Bm + (long)(blockIdx.y * 128 + si) * K + sk;

    f32x4 acc[4][4] = {};

    for (int k0 = 0; k0 < K; k0 += 32) {
        bf16x8 a0 = *(const bf16x8*)(Ap + k0);
        bf16x8 a1 = *(const bf16x8*)(Ap + (long)64 * K + k0);
        bf16x8 b0 = *(const bf16x8*)(Bp + k0);
        bf16x8 b1 = *(const bf16x8*)(Bp + (long)64 * K + k0);
        __syncthreads();
        *(bf16x8*)&As[si][sk]      = a0;
        *(bf16x8*)&As[si + 64][sk] = a1;
        *(bf16x8*)&Bs[si][sk]      = b0;
        *(bf16x8*)&Bs[si + 64][sk] = b1;
        __syncthreads();
        bf16x8 af[4], bfr[4];
#pragma unroll
        for (int i = 0; i < 4; i++) af[i] = *(const bf16x8*)&As[wm + i * 16 + lrow][quad * 8];
#pragma unroll
        for (int j = 0; j < 4; j++) bfr[j] = *(const bf16x8*)&Bs[wn + j * 16 + lrow][quad * 8];
#pragma unroll
        for (int i = 0; i < 4; i++)
#pragma unroll
            for (int j = 0; j < 4; j++)
                acc[i][j] = MFMA16(af[i], bfr[j], acc[i][j]);
    }

    const int gm0 = blockIdx.x * 128 + wm;
    const int go0 = blockIdx.y * 128 + wn;

    if (blockIdx.y < 16) {
        // Q (scaled by 0.125 = head_dim^-0.5, exact pow2) or K: [B][H][N][D]
        const bool isQ = blockIdx.y < 8;
        bf16* dst = isQ ? qo : ko;
        const float sc = isQ ? 0.125f : 1.0f;
#pragma unroll
        for (int i = 0; i < 4; i++) {
#pragma unroll
            for (int r = 0; r < 4; r++) {
                int gm = gm0 + i * 16 + quad * 4 + r;
                int b = gm >> 11, n = gm & 2047;
#pragma unroll
                for (int j = 0; j < 4; j++) {
                    int o = go0 + j * 16 + lrow;
                    int rem = o & 1023;
                    int h = rem >> 6, d = rem & 63;
                    long idx = (((long)(b * 16 + h)) * 2048 + n) * 64 + d;
                    dst[idx] = (bf16)(acc[i][j][r] * sc);
                }
            }
        }
    } else {
        // V: transposed store [B][H][D][N]; r runs along n -> bf16x4 rows
#pragma unroll
        for (int i = 0; i < 4; i++) {
            int gmb = gm0 + i * 16 + quad * 4;
            int b = gmb >> 11, nb = gmb & 2047;
#pragma unroll
            for (int j = 0; j < 4; j++) {
                int o = go0 + j * 16 + lrow;
                int rem = o & 1023;
                int h = rem >> 6, d = rem & 63;
                bf16x4 pk;
#pragma unroll
                for (int r = 0; r < 4; r++) pk[r] = (bf16)acc[i][j][r];
                *(bf16x4*)&vo[(((long)(b * 16 + h)) * 64 + d) * 2048 + nb] = pk;
            }
        }
    }
}

// ---------------- Flash attention (S^T formulation) ----------------
// q pre-scaled [B][H][N][D]; k [B][H][N][D]; vt [B][H][D][N]; o [B][N][H*D]
__global__ __launch_bounds__(256, 2) void attn_kernel(
    const bf16* __restrict__ q, const bf16* __restrict__ k,
    const bf16* __restrict__ vt, bf16* __restrict__ o)
{
    __shared__ bf16 Ks[64][72];    // [kpos][d]
    __shared__ bf16 Vts[64][72];   // [d][kpos] (V^T, loaded directly)
    __shared__ bf16 QP[128][72];   // Q staging, then per-wave P buffers (rows [32w,32w+32))

    const int tid = threadIdx.x, wave = tid >> 6, lane = tid & 63;
    const int lrow = lane & 15, quad = lane >> 4;
    const int bh = blockIdx.x, qt = blockIdx.y;
    const bf16* Qp = q + ((long)bh * 2048 + qt * 128) * 64;
    const bf16* Kp = k + (long)bh * 2048 * 64;
    const bf16* Vp = vt + (long)bh * 64 * 2048;

    // ---- stage Q (128x64), pull per-wave B-fragments into regs ----
    {
        int r0 = tid >> 3, g = (tid & 7) * 8;
#pragma unroll
        for (int p = 0; p < 4; p++)
            *(bf16x8*)&QP[r0 + p * 32][g] = *(const bf16x8*)&Qp[(r0 + p * 32) * 64 + g];
    }
    __syncthreads();
    bf16x8 qf[2][2];
#pragma unroll
    for (int t = 0; t < 2; t++)
#pragma unroll
        for (int ks = 0; ks < 2; ks++)
            qf[t][ks] = *(const bf16x8*)&QP[wave * 32 + t * 16 + lrow][ks * 32 + quad * 8];

    bf16(*Ps)[72] = (bf16(*)[72])QP + wave * 32;  // rows [0,32) per wave

    float mst[2] = {-1e30f, -1e30f}, lst[2] = {0.0f, 0.0f};
    f32x4 oacc[2][4] = {};

    for (int kv = 0; kv < 32; kv++) {
        const int r0 = tid >> 3, g = (tid & 7) * 8;
        const bf16* Kt = Kp + kv * 64 * 64;
        bf16x8 k0v = *(const bf16x8*)&Kt[r0 * 64 + g];
        bf16x8 k1v = *(const bf16x8*)&Kt[(r0 + 32) * 64 + g];
        bf16x8 v0v = *(const bf16x8*)&Vp[(long)r0 * 2048 + kv * 64 + g];
        bf16x8 v1v = *(const bf16x8*)&Vp[(long)(r0 + 32) * 2048 + kv * 64 + g];
        __syncthreads();   // prev iter's Ks/Vts reads (and iter-0 qf reads) complete
        *(bf16x8*)&Ks[r0][g]       = k0v;
        *(bf16x8*)&Ks[r0 + 32][g]  = k1v;
        *(bf16x8*)&Vts[r0][g]      = v0v;
        *(bf16x8*)&Vts[r0 + 32][g] = v1v;
        __syncthreads();

        // ---- S^T = K Q^T : sacc[t][n] rows = kpos (n*16+quad*4+reg), cols = q (t*16+lrow)
        f32x4 sacc[2][4] = {};
#pragma unroll
        for (int ks = 0; ks < 2; ks++) {
            bf16x8 kf[4];
#pragma unroll
            for (int n = 0; n < 4; n++) kf[n] = *(const bf16x8*)&Ks[n * 16 + lrow][ks * 32 + quad * 8];
#pragma unroll
            for (int t = 0; t < 2; t++)
#pragma unroll
                for (int n = 0; n < 4; n++)
                    sacc[t][n] = MFMA16(kf[n], qf[t][ks], sacc[t][n]);
        }

        // ---- online softmax: lane owns q = t*16+lrow; kpos spread over (n, quad, reg)
#pragma unroll
        for (int t = 0; t < 2; t++) {
            float mx = -1e30f;
#pragma unroll
            for (int n = 0; n < 4; n++)
#pragma unroll
                for (int r = 0; r < 4; r++) mx = fmaxf(mx, sacc[t][n][r]);
            mx = fmaxf(mx, __shfl_xor(mx, 16, 64));
            mx = fmaxf(mx, __shfl_xor(mx, 32, 64));
            float mnew = fmaxf(mst[t], mx);
            float alpha = __expf(mst[t] - mnew);
            mst[t] = mnew;
            float rsum = 0.0f;
#pragma unroll
            for (int n = 0; n < 4; n++) {
                bf16x4 pk;
#pragma unroll
                for (int r = 0; r < 4; r++) {
                    float p = __expf(sacc[t][n][r] - mnew);
                    rsum += p;
                    pk[r] = (bf16)p;
                }
                *(bf16x4*)&Ps[t * 16 + lrow][n * 16 + quad * 4] = pk;  // contiguous along kpos
            }
            rsum += __shfl_xor(rsum, 16, 64);
            rsum += __shfl_xor(rsum, 32, 64);
            lst[t] = lst[t] * alpha + rsum;
            // broadcast alpha to the lanes holding oacc rows q = quad*4+r
            float a0 = __shfl(alpha, quad * 4 + 0, 64);
            float a1 = __shfl(alpha, quad * 4 + 1, 64);
            float a2 = __shfl(alpha, quad * 4 + 2, 64);
            float a3 = __shfl(alpha, quad * 4 + 3, 64);
#pragma unroll
            for (int jd = 0; jd < 4; jd++) {
                oacc[t][jd][0] *= a0; oacc[t][jd][1] *= a1;
                oacc[t][jd][2] *= a2; oacc[t][jd][3] *= a3;
            }
        }

        // ---- O += P V  (P a-frags from per-wave LDS, V^T b-frags, no barrier needed)
#pragma unroll
        for (int c = 0; c < 2; c++) {
            bf16x8 vf[4];
#pragma unroll
            for (int jd = 0; jd < 4; jd++)
                vf[jd] = *(const bf16x8*)&Vts[jd * 16 + lrow][c * 32 + quad * 8];
#pragma unroll
            for (int t = 0; t < 2; t++) {
                bf16x8 pf = *(const bf16x8*)&Ps[t * 16 + lrow][c * 32 + quad * 8];
#pragma unroll
                for (int jd = 0; jd < 4; jd++)
                    oacc[t][jd] = MFMA16(pf, vf[jd], oacc[t][jd]);
            }
        }
    }

    // ---- epilogue: O /= l, write [B][N][H*D] ----
    const int b = bh >> 4, h = bh & 15;
#pragma unroll
    for (int t = 0; t < 2; t++) {
        float linv = 1.0f / lst[t];
#pragma unroll
        for (int r = 0; r < 4; r++) {
            float lr = __shfl(linv, quad * 4 + r, 64);
            int n = qt * 128 + wave * 32 + t * 16 + quad * 4 + r;
#pragma unroll
            for (int jd = 0; jd < 4; jd++)
                o[((long)(b * 2048 + n)) * 1024 + h * 64 + jd * 16 + lrow] = (bf16)(oacc[t][jd][r] * lr);
        }
    }
}

// ---------------- GEMM2: out = attn_out @ w_proj^T (fp32 out) ----------------
__global__ __launch_bounds__(256, 2) void gemm_proj(
    const bf16* __restrict__ A, const bf16* __restrict__ Bm, float* __restrict__ out)
{
    const int K = 1024;
    __shared__ bf16 As[128][40];
    __shared__ bf16 Bs[128][40];
    const int tid = threadIdx.x;
    const int wave = tid >> 6, lane = tid & 63;
    const int lrow = lane & 15, quad = lane >> 4;
    const int wm = (wave >> 1) * 64, wn = (wave & 1) * 64;
    const int si = tid >> 2, sk = (tid & 3) * 8;

    const bf16* Ap = A + (long)(blockIdx.x * 128 + si) * K + sk;
    const bf16* Bp = Bm + (long)(blockIdx.y * 128 + si) * K + sk;

    f32x4 acc[4][4] = {};

    for (int k0 = 0; k0 < K; k0 += 32) {
        bf16x8 a0 = *(const bf16x8*)(Ap + k0);
        bf16x8 a1 = *(const bf16x8*)(Ap + (long)64 * K + k0);
        bf16x8 b0 = *(const bf16x8*)(Bp + k0);
        bf16x8 b1 = *(const bf16x8*)(Bp + (long)64 * K + k0);
        __syncthreads();
        *(bf16x8*)&As[si][sk]      = a0;
        *(bf16x8*)&As[si + 64][sk] = a1;
        *(bf16x8*)&Bs[si][sk]      = b0;
        *(bf16x8*)&Bs[si + 64][sk] = b1;
        __syncthreads();
        bf16x8 af[4], bfr[4];
#pragma unroll
        for (int i = 0; i < 4; i++) af[i] = *(const bf16x8*)&As[wm + i * 16 + lrow][quad * 8];
#pragma unroll
        for (int j = 0; j < 4; j++) bfr[j] = *(const bf16x8*)&Bs[wn + j * 16 + lrow][quad * 8];
#pragma unroll
        for (int i = 0; i < 4; i++)
#pragma unroll
            for (int j = 0; j < 4; j++)
                acc[i][j] = MFMA16(af[i], bfr[j], acc[i][j]);
    }

    const int gm0 = blockIdx.x * 128 + wm;
    const int go0 = blockIdx.y * 128 + wn;
#pragma unroll
    for (int i = 0; i < 4; i++)
#pragma unroll
        for (int r = 0; r < 4; r++) {
            int gm = gm0 + i * 16 + quad * 4 + r;
#pragma unroll
            for (int j = 0; j < 4; j++) {
                int o = go0 + j * 16 + lrow;
                out[(long)gm * 1024 + o] = acc[i][j][r];
            }
        }
}

// ---------------- launch ----------------
extern "C" void kernel_launch(void* const* d_in, const int* in_sizes, int n_in,
                              void* d_out, int out_size, void* d_ws, size_t ws_size,
                              hipStream_t stream) {
    const float* x      = (const float*)d_in[0];   // [2,2048,1024]
    const float* w_qkv  = (const float*)d_in[1];   // [3072,1024]
    const float* w_proj = (const float*)d_in[2];   // [1024,1024]
    float* out = (float*)d_out;                    // [2,2048,1024]

    bf16* ws = (bf16*)d_ws;
    bf16* xb     = ws;                       // 4096*1024
    bf16* wqkvb  = xb + 4096 * 1024;         // 3072*1024
    bf16* wprojb = wqkvb + 3072 * 1024;      // 1024*1024
    bf16* qb     = wprojb + 1024 * 1024;     // [2][16][2048][64]
    bf16* kb     = qb + 2 * 16 * 2048 * 64;  // [2][16][2048][64]
    bf16* vb     = kb + 2 * 16 * 2048 * 64;  // [2][16][64][2048]  (V^T)
    bf16* ob     = vb + 2 * 16 * 2048 * 64;  // 4096*1024

    cvt_kernel<<<(4096 * 1024 / 4 + 255) / 256, 256, 0, stream>>>(x, xb, 4096 * 1024 / 4);
    cvt_kernel<<<(3072 * 1024 / 4 + 255) / 256, 256, 0, stream>>>(w_qkv, wqkvb, 3072 * 1024 / 4);
    cvt_kernel<<<(1024 * 1024 / 4 + 255) / 256, 256, 0, stream>>>(w_proj, wprojb, 1024 * 1024 / 4);

    gemm_qkv<<<dim3(32, 24), 256, 0, stream>>>(xb, wqkvb, qb, kb, vb);
    attn_kernel<<<dim3(32, 16), 256, 0, stream>>>(qb, kb, vb, ob);
    gemm_proj<<<dim3(32, 8), 256, 0, stream>>>(ob, wprojb, out);
}